// Round 4
// baseline (1197.198 us; speedup 1.0000x reference)
//
#include <hip/hip_runtime.h>
#include <cmath>

// Problem constants
#define NB 8
#define NPTS 4096
#define NPT 1024
#define NSAMP 32
#define MTOT (NB*NPT*NSAMP)   // 262144 rows for the MLP
#define NBLK 4096             // MTOT/64 GEMM blocks

typedef float v2f __attribute__((ext_vector_type(2)));

// ---------------------------------------------------------------------------
// Stage 1: farthest point sampling. One block per batch. Bitwise-exact f32
// replication of the reference (packed mul/add with contraction OFF keeps the
// separate-rounding mul-then-add order; (dx2+dy2)+dz2 sum order; argmax with
// first-index tie-break via u64 key). The winner's COORDINATES are carried
// through the DPP + LDS reduction, so the next step's centroid comes out of
// the reduction tail directly — no dependent sxyz[far] LDS read per step.
// ---------------------------------------------------------------------------
#define DPP_XSTAGE(CTRL) do {                                                  \
    unsigned int olo = (unsigned int)__builtin_amdgcn_update_dpp(              \
        0, (int)lo, (CTRL), 0xf, 0xf, false);                                  \
    unsigned int ohi = (unsigned int)__builtin_amdgcn_update_dpp(              \
        0, (int)hi, (CTRL), 0xf, 0xf, false);                                  \
    int ocx = __builtin_amdgcn_update_dpp(                                     \
        0, __float_as_int(kcx), (CTRL), 0xf, 0xf, false);                      \
    int ocy = __builtin_amdgcn_update_dpp(                                     \
        0, __float_as_int(kcy), (CTRL), 0xf, 0xf, false);                      \
    int ocz = __builtin_amdgcn_update_dpp(                                     \
        0, __float_as_int(kcz), (CTRL), 0xf, 0xf, false);                      \
    unsigned long long other = ((unsigned long long)ohi << 32) | olo;          \
    bool take = other > key;   /* invalid lanes inject key=0: never taken */   \
    key = take ? other : key;                                                  \
    kcx = take ? __int_as_float(ocx) : kcx;                                    \
    kcy = take ? __int_as_float(ocy) : kcy;                                    \
    kcz = take ? __int_as_float(ocz) : kcz;                                    \
    lo = (unsigned int)key; hi = (unsigned int)(key >> 32);                    \
  } while (0)

__global__ __launch_bounds__(256) void fps_kernel(const float* __restrict__ xyz,
                                                  float* __restrict__ new_xyz) {
#pragma clang fp contract(off)
  const int b = blockIdx.x;
  const int t = threadIdx.x;
  __shared__ unsigned long long rkey[2][4];
  __shared__ float4 rc[2][4];
  const float* X = xyz + (size_t)b * NPTS * 3;
  v2f px[8], py[8], pz[8], dist[8];
#pragma unroll
  for (int i = 0; i < 8; ++i) {
    int p0 = (2 * i) * 256 + t;
    int p1 = (2 * i + 1) * 256 + t;
    float x0 = X[p0 * 3 + 0], y0 = X[p0 * 3 + 1], z0 = X[p0 * 3 + 2];
    float x1 = X[p1 * 3 + 0], y1 = X[p1 * 3 + 1], z1 = X[p1 * 3 + 2];
    px[i] = (v2f){x0, x1}; py[i] = (v2f){y0, y1}; pz[i] = (v2f){z0, z1};
    dist[i] = (v2f){1e10f, 1e10f};
  }
  // first centroid = point 0 (reference: farthest starts at 0)
  float ccx = X[0], ccy = X[1], ccz = X[2];
  float* outp = new_xyz + (size_t)b * NPT * 3;
  for (int s = 0; s < NPT; ++s) {
    if (t == 0) { outp[s * 3 + 0] = ccx; outp[s * 3 + 1] = ccy; outp[s * 3 + 2] = ccz; }
    v2f cx = (v2f){ccx, ccx}, cy = (v2f){ccy, ccy}, cz = (v2f){ccz, ccz};
    float bestv = -1.0f; int besti = 0;
#pragma unroll
    for (int i = 0; i < 8; ++i) {
      v2f dx = px[i] - cx;
      v2f dy = py[i] - cy;
      v2f dz = pz[i] - cz;
      v2f d = (dx * dx + dy * dy) + dz * dz;    // contract(off): mul/add, ref order
      v2f nd = __builtin_elementwise_min(dist[i], d);
      dist[i] = nd;
      // ascending point-index scan -> strict > keeps lowest index on tie
      if (nd.x > bestv) { bestv = nd.x; besti = (2 * i) * 256 + t; }
      if (nd.y > bestv) { bestv = nd.y; besti = (2 * i + 1) * 256 + t; }
    }
    // select this thread's best candidate coords from registers (cndmask tree;
    // depends only on besti — issues into the DPP stall gaps)
    int slot = besti >> 9;             // which v2f register
    bool odd = (besti >> 8) & 1;       // .y half?
    bool b0 = slot & 1, b1 = slot & 2, b2 = slot & 4;
    v2f x01 = b0 ? px[1] : px[0], x23 = b0 ? px[3] : px[2];
    v2f x45 = b0 ? px[5] : px[4], x67 = b0 ? px[7] : px[6];
    v2f y01 = b0 ? py[1] : py[0], y23 = b0 ? py[3] : py[2];
    v2f y45 = b0 ? py[5] : py[4], y67 = b0 ? py[7] : py[6];
    v2f z01 = b0 ? pz[1] : pz[0], z23 = b0 ? pz[3] : pz[2];
    v2f z45 = b0 ? pz[5] : pz[4], z67 = b0 ? pz[7] : pz[6];
    v2f xq = b2 ? (b1 ? x67 : x45) : (b1 ? x23 : x01);
    v2f yq = b2 ? (b1 ? y67 : y45) : (b1 ? y23 : y01);
    v2f zq = b2 ? (b1 ? z67 : z45) : (b1 ? z23 : z01);
    float kcx = odd ? xq.y : xq.x;
    float kcy = odd ? yq.y : yq.x;
    float kcz = odd ? zq.y : zq.x;
    // pack: higher value wins; equal value -> smaller index wins
    unsigned long long key = ((unsigned long long)__float_as_uint(bestv) << 32)
                           | (unsigned int)(~besti);
    unsigned int lo = (unsigned int)key, hi = (unsigned int)(key >> 32);
    // wave64 max-reduce via DPP, coords ride along; result in lane 63
    DPP_XSTAGE(0x111);   // row_shr:1
    DPP_XSTAGE(0x112);   // row_shr:2
    DPP_XSTAGE(0x114);   // row_shr:4
    DPP_XSTAGE(0x118);   // row_shr:8
    DPP_XSTAGE(0x142);   // row_bcast:15
    DPP_XSTAGE(0x143);   // row_bcast:31
    int par = s & 1;
    if ((t & 63) == 63) {
      rkey[par][t >> 6] = key;
      rc[par][t >> 6] = make_float4(kcx, kcy, kcz, 0.0f);
    }
    __syncthreads();
    unsigned long long ka = rkey[par][0], kb = rkey[par][1];
    unsigned long long kc = rkey[par][2], kd = rkey[par][3];
    float4 ca = rc[par][0], cb = rc[par][1], cc = rc[par][2], cd = rc[par][3];
    bool tab = kb > ka;
    unsigned long long k01 = tab ? kb : ka;
    float4 c01; c01.x = tab ? cb.x : ca.x; c01.y = tab ? cb.y : ca.y; c01.z = tab ? cb.z : ca.z;
    bool tcd = kd > kc;
    unsigned long long k23 = tcd ? kd : kc;
    float4 c23; c23.x = tcd ? cd.x : cc.x; c23.y = tcd ? cd.y : cc.y; c23.z = tcd ? cd.z : cc.z;
    bool tf = k23 > k01;
    ccx = tf ? c23.x : c01.x;
    ccy = tf ? c23.y : c01.y;
    ccz = tf ? c23.z : c01.z;
  }
}

// ---------------------------------------------------------------------------
// Stage 2: ball query. One wave per (b,s). First 32 indices in ascending order
// with dist <= r^2; pad with first match.
// ---------------------------------------------------------------------------
__global__ __launch_bounds__(256) void ballq_kernel(const float* __restrict__ xyz,
                                                    const float* __restrict__ new_xyz,
                                                    int* __restrict__ gidx) {
  int w = (blockIdx.x * 256 + threadIdx.x) >> 6;   // 8192 waves
  int lane = threadIdx.x & 63;
  int b = w >> 10;
  const float* X = xyz + (size_t)b * NPTS * 3;
  float cx = new_xyz[w * 3 + 0], cy = new_xyz[w * 3 + 1], cz = new_xyz[w * 3 + 2];
  int* out = gidx + (size_t)w * NSAMP;
  int cnt = 0, first = -1;
  for (int c = 0; c < NPTS / 64; ++c) {
    int p = c * 64 + lane;
    float dx = __fsub_rn(X[p * 3 + 0], cx);
    float dy = __fsub_rn(X[p * 3 + 1], cy);
    float dz = __fsub_rn(X[p * 3 + 2], cz);
    float d = __fadd_rn(__fadd_rn(__fmul_rn(dx, dx), __fmul_rn(dy, dy)), __fmul_rn(dz, dz));
    bool inr = !(d > 0.04f);   // f32(0.2**2) == 0.04f
    unsigned long long mask = __ballot(inr);
    if (mask) {
      if (first < 0) first = c * 64 + (int)__builtin_ctzll(mask);
      if (inr) {
        int pos = cnt + (int)__builtin_popcountll(mask & ((1ull << lane) - 1ull));
        if (pos < NSAMP) out[pos] = p;
      }
      cnt += (int)__builtin_popcountll(mask);
      if (cnt >= NSAMP) break;
    }
  }
  if (lane >= cnt && lane < NSAMP) out[lane] = first;
}

// ---------------------------------------------------------------------------
// Stage 3: gather + concat -> X0 (MTOT x 68, col67 zero pad)
// ---------------------------------------------------------------------------
__global__ __launch_bounds__(256) void gather_kernel(const float* __restrict__ xyz,
                                                     const float* __restrict__ points,
                                                     const float* __restrict__ new_xyz,
                                                     const int* __restrict__ gidx,
                                                     float* __restrict__ X0) {
  int gid = blockIdx.x * 256 + threadIdx.x;       // < MTOT*68 exactly
  int m = gid / 68;
  int c = gid - m * 68;
  int idx = gidx[m];
  int b = m >> 15;                                 // 32768 rows per batch
  float v;
  if (c < 3) {
    v = __fsub_rn(xyz[((size_t)b * NPTS + idx) * 3 + c],
                  new_xyz[(size_t)(m >> 5) * 3 + c]);
  } else if (c < 67) {
    v = points[((size_t)b * NPTS + idx) * 64 + (c - 3)];
  } else {
    v = 0.0f;
  }
  X0[gid] = v;
}

// ---------------------------------------------------------------------------
// Stage 4: MLP layer GEMM. 64xO tile per block, 256 threads.
// Thread (to=t&15, tm=t>>4) computes rows 4*tm..+3, cols OJ*to..+OJ-1.
// Optionally applies previous layer's BN+ReLU (a,d) while staging input.
// Writes per-block per-channel sum / sumsq partials (deterministic stats).
// DO_MM: instead of writing Y, max/min-pool pre-activations over k (32 rows).
// ---------------------------------------------------------------------------
template<int KDIM, int XSTRIDE, int O, bool NORM_IN, bool WRITE_Y, bool DO_MM>
__global__ __launch_bounds__(256) void mlp_gemm(const float* __restrict__ Xg,
                                                const float* __restrict__ Wg,
                                                const float* __restrict__ bias,
                                                const float* __restrict__ ad,
                                                float* __restrict__ Yg,
                                                float* __restrict__ partials,
                                                float* __restrict__ mm) {
  constexpr int KP = (KDIM + 3) & ~3;   // 68 or 64
  constexpr int KP4 = KP / 4;
  constexpr int OJ = O / 16;            // 4 or 8
  __shared__ __align__(16) float sX[64 * 68];
  __shared__ __align__(16) float sWt[KP * O];
  const int t = threadIdx.x;
  const int m0 = blockIdx.x * 64;

  // stage W transposed: sWt[k*O+o] = W[o*KDIM+k]; consecutive t -> consecutive o
  for (int i = t; i < O * KDIM; i += 256) {
    int k = i / O;            // O is power of 2
    int o = i - k * O;
    sWt[k * O + o] = Wg[o * KDIM + k];
  }
  if (KP > KDIM) {
    if (t < O) {
      for (int k = KDIM; k < KP; ++k) sWt[k * O + t] = 0.0f;
    }
  }
  // stage X tile (apply BN+ReLU of previous layer if NORM_IN)
  {
    int r = t >> 2, q = t & 3;
    const float* src = Xg + (size_t)(m0 + r) * XSTRIDE;
    for (int c4 = q; c4 < KP4; c4 += 4) {
      float4 v = *(const float4*)(src + 4 * c4);
      if constexpr (NORM_IN) {
        float4 a = *(const float4*)(ad + 4 * c4);
        float4 d = *(const float4*)(ad + 128 + 4 * c4);
        v.x = fmaxf(fmaf(a.x, v.x, d.x), 0.0f);
        v.y = fmaxf(fmaf(a.y, v.y, d.y), 0.0f);
        v.z = fmaxf(fmaf(a.z, v.z, d.z), 0.0f);
        v.w = fmaxf(fmaf(a.w, v.w, d.w), 0.0f);
      }
      *(float4*)&sX[r * 68 + 4 * c4] = v;
    }
  }
  __syncthreads();

  const int to = t & 15, tm = t >> 4;
  float acc[4][OJ];
#pragma unroll
  for (int i = 0; i < 4; ++i)
#pragma unroll
    for (int j = 0; j < OJ; ++j) acc[i][j] = 0.0f;

#pragma unroll
  for (int k4 = 0; k4 < KP4; ++k4) {
    float xs[4][4];
#pragma unroll
    for (int i = 0; i < 4; ++i) {
      float4 v = *(const float4*)&sX[(4 * tm + i) * 68 + 4 * k4];
      xs[i][0] = v.x; xs[i][1] = v.y; xs[i][2] = v.z; xs[i][3] = v.w;
    }
#pragma unroll
    for (int kk = 0; kk < 4; ++kk) {
      float wv[OJ];
#pragma unroll
      for (int j4 = 0; j4 < OJ / 4; ++j4) {
        float4 wq = *(const float4*)&sWt[(4 * k4 + kk) * O + OJ * to + 4 * j4];
        wv[4 * j4 + 0] = wq.x; wv[4 * j4 + 1] = wq.y;
        wv[4 * j4 + 2] = wq.z; wv[4 * j4 + 3] = wq.w;
      }
#pragma unroll
      for (int i = 0; i < 4; ++i) {
        float xv = xs[i][kk];
#pragma unroll
        for (int j = 0; j < OJ; ++j) acc[i][j] = fmaf(xv, wv[j], acc[i][j]);
      }
    }
  }
  // bias
#pragma unroll
  for (int j = 0; j < OJ; ++j) {
    float bb = bias[OJ * to + j];
#pragma unroll
    for (int i = 0; i < 4; ++i) acc[i][j] += bb;
  }
  // stats partials: sum / sumsq over the 64 rows of this block
  float ps[OJ], ss[OJ];
#pragma unroll
  for (int j = 0; j < OJ; ++j) {
    ps[j] = ((acc[0][j] + acc[1][j]) + (acc[2][j] + acc[3][j]));
    ss[j] = ((acc[0][j] * acc[0][j] + acc[1][j] * acc[1][j]) +
             (acc[2][j] * acc[2][j] + acc[3][j] * acc[3][j]));
  }
  __syncthreads();   // done reading sX; reuse as reduction scratch (32*O <= 4352)
#pragma unroll
  for (int j = 0; j < OJ; ++j) {
    int o = OJ * to + j;
    sX[tm * O + o] = ps[j];
    sX[16 * O + tm * O + o] = ss[j];
  }
  __syncthreads();
  if (t < O) {
    float s1 = 0.0f, s2 = 0.0f;
#pragma unroll
    for (int r2 = 0; r2 < 16; ++r2) { s1 += sX[r2 * O + t]; s2 += sX[16 * O + r2 * O + t]; }
    partials[(size_t)t * NBLK + blockIdx.x] = s1;
    partials[(size_t)(O + t) * NBLK + blockIdx.x] = s2;
  }
  if constexpr (WRITE_Y) {
#pragma unroll
    for (int i = 0; i < 4; ++i) {
#pragma unroll
      for (int j4 = 0; j4 < OJ / 4; ++j4) {
        *(float4*)&Yg[(size_t)(m0 + 4 * tm + i) * O + OJ * to + 4 * j4] =
            make_float4(acc[i][4 * j4 + 0], acc[i][4 * j4 + 1],
                        acc[i][4 * j4 + 2], acc[i][4 * j4 + 3]);
      }
    }
  }
  if constexpr (DO_MM) {
    // per-thread max/min over its 4 rows (all in the same k-group of 32)
    float vmx[OJ], vmn[OJ];
#pragma unroll
    for (int j = 0; j < OJ; ++j) {
      vmx[j] = fmaxf(fmaxf(acc[0][j], acc[1][j]), fmaxf(acc[2][j], acc[3][j]));
      vmn[j] = fminf(fminf(acc[0][j], acc[1][j]), fminf(acc[2][j], acc[3][j]));
    }
    __syncthreads();
#pragma unroll
    for (int j = 0; j < OJ; ++j) {
      int o = OJ * to + j;
      sX[tm * O + o] = vmx[j];
      sX[16 * O + tm * O + o] = vmn[j];
    }
    __syncthreads();
    // 256 threads = 2 groups x O(=128)
    int g = t >> 7, o = t & 127;
    float mx = sX[(g * 8) * O + o];
    float mn = sX[16 * O + (g * 8) * O + o];
#pragma unroll
    for (int r2 = 1; r2 < 8; ++r2) {
      mx = fmaxf(mx, sX[(g * 8 + r2) * O + o]);
      mn = fminf(mn, sX[16 * O + (g * 8 + r2) * O + o]);
    }
    int row = (m0 >> 5) + g;                   // (b,s) index
    mm[(size_t)row * O + o] = mx;
    mm[(size_t)8192 * O + (size_t)row * O + o] = mn;
  }
}

// ---------------------------------------------------------------------------
// BN finalize: reduce 4096 partials per channel -> (a, d) with a=g*rsigma,
// d = bt - mu*a. ad layout: a at [0..O), d at [128..128+O).
// ---------------------------------------------------------------------------
__global__ __launch_bounds__(256) void bn_finalize(const float* __restrict__ partials,
                                                   const float* __restrict__ g,
                                                   const float* __restrict__ bt,
                                                   float* __restrict__ ad, int O) {
  int o = blockIdx.x, t = threadIdx.x;
  const float* p1 = partials + (size_t)o * NBLK;
  const float* p2 = partials + (size_t)(O + o) * NBLK;
  float s1 = 0.0f, s2 = 0.0f;
  for (int i = t; i < NBLK; i += 256) { s1 += p1[i]; s2 += p2[i]; }
  __shared__ float r1[4], r2[4];
#pragma unroll
  for (int off = 32; off >= 1; off >>= 1) {
    s1 += __shfl_down(s1, off, 64);
    s2 += __shfl_down(s2, off, 64);
  }
  if ((t & 63) == 0) { r1[t >> 6] = s1; r2[t >> 6] = s2; }
  __syncthreads();
  if (t == 0) {
    float S1 = (r1[0] + r1[1]) + (r1[2] + r1[3]);
    float S2 = (r2[0] + r2[1]) + (r2[2] + r2[3]);
    const float invM = 1.0f / (float)MTOT;
    float mu = S1 * invM;
    float var = S2 * invM - mu * mu;
    float rs = 1.0f / sqrtf(var + 1e-5f);
    float a = g[o] * rs;
    ad[o] = a;
    ad[128 + o] = bt[o] - mu * a;
  }
}

// ---------------------------------------------------------------------------
// Final: new_points[(b,s),o] = relu(a * (a>=0 ? max : min) + d)
// ---------------------------------------------------------------------------
__global__ __launch_bounds__(256) void final_kernel(const float* __restrict__ mm,
                                                    const float* __restrict__ ad,
                                                    float* __restrict__ out) {
  int gid = blockIdx.x * 256 + threadIdx.x;   // 8192*128 exactly
  int o = gid & 127;
  float a = ad[o], d = ad[128 + o];
  float y = (a >= 0.0f) ? mm[gid] : mm[8192 * 128 + gid];
  out[gid] = fmaxf(fmaf(a, y, d), 0.0f);
}

extern "C" void kernel_launch(void* const* d_in, const int* in_sizes, int n_in,
                              void* d_out, int out_size, void* d_ws, size_t ws_size,
                              hipStream_t stream) {
  (void)in_sizes; (void)n_in; (void)out_size; (void)ws_size;
  const float* xyz    = (const float*)d_in[0];
  const float* points = (const float*)d_in[1];
  const float* w0  = (const float*)d_in[2];
  const float* b0  = (const float*)d_in[3];
  const float* g0  = (const float*)d_in[4];
  const float* bt0 = (const float*)d_in[5];
  const float* w1  = (const float*)d_in[6];
  const float* b1  = (const float*)d_in[7];
  const float* g1  = (const float*)d_in[8];
  const float* bt1 = (const float*)d_in[9];
  const float* w2  = (const float*)d_in[10];
  const float* b2  = (const float*)d_in[11];
  const float* g2  = (const float*)d_in[12];
  const float* bt2 = (const float*)d_in[13];

  float* out      = (float*)d_out;
  float* new_xyz  = out;                 // 8*1024*3 = 24576 floats
  float* out_pts  = out + 24576;         // 8*1024*128 floats

  float* wsf  = (float*)d_ws;
  int*   gidx = (int*)d_ws;                          // 262144 ints
  float* X0   = wsf + 262144;                        // 262144*68
  float* Y1   = X0 + (size_t)MTOT * 68;              // 262144*64
  float* Y2   = X0;                                  // reuse X0 region
  float* part = Y1 + (size_t)MTOT * 64;              // 2*128*4096
  float* ad1  = part + 2 * 128 * NBLK;               // 256
  float* ad2  = ad1 + 256;
  float* ad3  = ad2 + 256;
  float* mm   = ad3 + 256;                           // 2*8192*128

  fps_kernel<<<NB, 256, 0, stream>>>(xyz, new_xyz);
  ballq_kernel<<<(NB * NPT * 64) / 256, 256, 0, stream>>>(xyz, new_xyz, gidx);
  gather_kernel<<<(MTOT * 68) / 256, 256, 0, stream>>>(xyz, points, new_xyz, gidx, X0);

  mlp_gemm<67, 68, 64, false, true, false><<<NBLK, 256, 0, stream>>>(
      X0, w0, b0, nullptr, Y1, part, nullptr);
  bn_finalize<<<64, 256, 0, stream>>>(part, g0, bt0, ad1, 64);

  mlp_gemm<64, 64, 64, true, true, false><<<NBLK, 256, 0, stream>>>(
      Y1, w1, b1, ad1, Y2, part, nullptr);
  bn_finalize<<<64, 256, 0, stream>>>(part, g1, bt1, ad2, 64);

  mlp_gemm<64, 64, 128, true, false, true><<<NBLK, 256, 0, stream>>>(
      Y2, w2, b2, ad2, nullptr, part, mm);
  bn_finalize<<<128, 256, 0, stream>>>(part, g2, bt2, ad3, 128);

  final_kernel<<<(8192 * 128) / 256, 256, 0, stream>>>(mm, ad3, out_pts);
}

// Round 5
// 990.348 us; speedup vs baseline: 1.2089x; 1.2089x over previous
//
#include <hip/hip_runtime.h>
#include <cmath>

// Problem constants
#define NB 8
#define NPTS 4096
#define NPT 1024
#define NSAMP 32
#define MTOT (NB*NPT*NSAMP)   // 262144 rows for the MLP
#define NBLK 4096             // MTOT/64 GEMM blocks

typedef float v2f __attribute__((ext_vector_type(2)));

// ---------------------------------------------------------------------------
// Stage 1: farthest point sampling. One block per batch (4 waves).
// Bitwise-exact f32 replication of the reference (packed mul/add with
// contraction OFF; (dx2+dy2)+dz2 order; argmax first-index tie-break).
// Per-step structure minimizes serial cmp/cndmask work:
//   - in-lane argmax: pk_max value tree + integer bit-equality mask + ctz
//     (vcc-free, latency-flat) instead of a 16-deep cmp/sel chain
//   - candidate coords: speculative per-lane ds_read_b128 (hidden under DPP)
//   - wave reduce: key-only u64 DPP max; winner lane found by readlane+cmp
//   - winner lane writes (key, coords) to slot; post-barrier 4-way merge
//   - no global stores in loop (centroids buffered in LDS, epilogue store)
// ---------------------------------------------------------------------------
#define DPP_STAGE(CTRL) do {                                                   \
    unsigned int olo = (unsigned int)__builtin_amdgcn_update_dpp(              \
        0, (int)lo, (CTRL), 0xf, 0xf, false);                                  \
    unsigned int ohi = (unsigned int)__builtin_amdgcn_update_dpp(              \
        0, (int)hi, (CTRL), 0xf, 0xf, false);                                  \
    unsigned long long other = ((unsigned long long)ohi << 32) | olo;          \
    if (other > key) key = other;                                              \
    lo = (unsigned int)key; hi = (unsigned int)(key >> 32);                    \
  } while (0)

__global__ __launch_bounds__(256) void fps_kernel(const float* __restrict__ xyz,
                                                  float* __restrict__ new_xyz) {
#pragma clang fp contract(off)
  const int b = blockIdx.x;
  const int t = threadIdx.x;
  const int wv = t >> 6;
  __shared__ float4 sxyz[NPTS];                 // 64 KiB
  __shared__ float4 sout[NPT];                  // 16 KiB centroid history
  __shared__ unsigned long long skey[2][4];
  __shared__ float4 scoord[2][4];
  const float* X = xyz + (size_t)b * NPTS * 3;
  v2f px[8], py[8], pz[8], dist[8];
#pragma unroll
  for (int i = 0; i < 8; ++i) {
    int p0 = (2 * i) * 256 + t;
    int p1 = (2 * i + 1) * 256 + t;
    float x0 = X[p0 * 3 + 0], y0 = X[p0 * 3 + 1], z0 = X[p0 * 3 + 2];
    float x1 = X[p1 * 3 + 0], y1 = X[p1 * 3 + 1], z1 = X[p1 * 3 + 2];
    px[i] = (v2f){x0, x1}; py[i] = (v2f){y0, y1}; pz[i] = (v2f){z0, z1};
    sxyz[p0] = make_float4(x0, y0, z0, 0.0f);
    sxyz[p1] = make_float4(x1, y1, z1, 0.0f);
    dist[i] = (v2f){1e10f, 1e10f};
  }
  __syncthreads();
  float ccx = X[0], ccy = X[1], ccz = X[2];     // first centroid = point 0
  for (int s = 0; s < NPT; ++s) {
    if (t == 0) sout[s] = make_float4(ccx, ccy, ccz, 0.0f);
    v2f cx = (v2f){ccx, ccx}, cy = (v2f){ccy, ccy}, cz = (v2f){ccz, ccz};
    v2f nd[8];
#pragma unroll
    for (int i = 0; i < 8; ++i) {
      v2f dx = px[i] - cx;
      v2f dy = py[i] - cy;
      v2f dz = pz[i] - cz;
      v2f d = (dx * dx + dy * dy) + dz * dz;    // contract(off): mul/add, ref order
      v2f m = __builtin_elementwise_min(dist[i], d);
      dist[i] = m;
      nd[i] = m;
    }
    // value max via pk tree (no index tracking)
    v2f m01 = __builtin_elementwise_max(nd[0], nd[1]);
    v2f m23 = __builtin_elementwise_max(nd[2], nd[3]);
    v2f m45 = __builtin_elementwise_max(nd[4], nd[5]);
    v2f m67 = __builtin_elementwise_max(nd[6], nd[7]);
    v2f m03 = __builtin_elementwise_max(m01, m23);
    v2f m47 = __builtin_elementwise_max(m45, m67);
    v2f mm2 = __builtin_elementwise_max(m03, m47);
    float maxv = fmaxf(mm2.x, mm2.y);
    // index recovery: integer bit-equality mask (vcc-free), ctz -> lowest ordinal
    unsigned mv = __float_as_uint(maxv);
    unsigned mask = 0;
#pragma unroll
    for (int i = 0; i < 8; ++i) {
      unsigned xl = __float_as_uint(nd[i].x) ^ mv;
      unsigned xh = __float_as_uint(nd[i].y) ^ mv;
      mask |= ((min(xl, 1u) ^ 1u) << (2 * i)) | ((min(xh, 1u) ^ 1u) << (2 * i + 1));
    }
    int i0 = __builtin_ctz(mask);               // smallest ordinal == smallest global idx
    int besti = (i0 << 8) + t;                  // ordinal*256 + t
    // speculative candidate coords (latency hidden under the DPP chain)
    float4 cand = sxyz[besti];
    // pack: higher value wins; equal value -> smaller index wins
    unsigned long long key = ((unsigned long long)mv << 32) | (unsigned int)(~besti);
    const unsigned long long mykey = key;
    unsigned int lo = (unsigned int)key, hi = (unsigned int)(key >> 32);
    DPP_STAGE(0x111);   // row_shr:1
    DPP_STAGE(0x112);   // row_shr:2
    DPP_STAGE(0x114);   // row_shr:4
    DPP_STAGE(0x118);   // row_shr:8
    DPP_STAGE(0x142);   // row_bcast:15
    DPP_STAGE(0x143);   // row_bcast:31
    unsigned wlo = (unsigned)__builtin_amdgcn_readlane((int)lo, 63);
    unsigned whi = (unsigned)__builtin_amdgcn_readlane((int)hi, 63);
    unsigned long long wkey = ((unsigned long long)whi << 32) | wlo;
    int par = s & 1;
    if (mykey == wkey) {                         // unique winner lane per wave
      skey[par][wv] = wkey;
      scoord[par][wv] = cand;
    }
    __syncthreads();
    unsigned long long k0 = skey[par][0], k1 = skey[par][1];
    unsigned long long k2 = skey[par][2], k3 = skey[par][3];
    float4 c0 = scoord[par][0], c1 = scoord[par][1];
    float4 c2 = scoord[par][2], c3 = scoord[par][3];
    bool tab = k1 > k0;
    unsigned long long k01 = tab ? k1 : k0;
    float ax = tab ? c1.x : c0.x, ay = tab ? c1.y : c0.y, az = tab ? c1.z : c0.z;
    bool tcd = k3 > k2;
    unsigned long long k23 = tcd ? k3 : k2;
    float bx = tcd ? c3.x : c2.x, by = tcd ? c3.y : c2.y, bz = tcd ? c3.z : c2.z;
    bool tf = k23 > k01;
    ccx = tf ? bx : ax;
    ccy = tf ? by : ay;
    ccz = tf ? bz : az;
  }
  __syncthreads();
  float* outp = new_xyz + (size_t)b * NPT * 3;
  for (int j = t; j < NPT; j += 256) {
    float4 c = sout[j];
    outp[3 * j + 0] = c.x; outp[3 * j + 1] = c.y; outp[3 * j + 2] = c.z;
  }
}

// ---------------------------------------------------------------------------
// Stage 2: ball query. One wave per (b,s). First 32 indices in ascending order
// with dist <= r^2; pad with first match.
// ---------------------------------------------------------------------------
__global__ __launch_bounds__(256) void ballq_kernel(const float* __restrict__ xyz,
                                                    const float* __restrict__ new_xyz,
                                                    int* __restrict__ gidx) {
  int w = (blockIdx.x * 256 + threadIdx.x) >> 6;   // 8192 waves
  int lane = threadIdx.x & 63;
  int b = w >> 10;
  const float* X = xyz + (size_t)b * NPTS * 3;
  float cx = new_xyz[w * 3 + 0], cy = new_xyz[w * 3 + 1], cz = new_xyz[w * 3 + 2];
  int* out = gidx + (size_t)w * NSAMP;
  int cnt = 0, first = -1;
  for (int c = 0; c < NPTS / 64; ++c) {
    int p = c * 64 + lane;
    float dx = __fsub_rn(X[p * 3 + 0], cx);
    float dy = __fsub_rn(X[p * 3 + 1], cy);
    float dz = __fsub_rn(X[p * 3 + 2], cz);
    float d = __fadd_rn(__fadd_rn(__fmul_rn(dx, dx), __fmul_rn(dy, dy)), __fmul_rn(dz, dz));
    bool inr = !(d > 0.04f);   // f32(0.2**2) == 0.04f
    unsigned long long mask = __ballot(inr);
    if (mask) {
      if (first < 0) first = c * 64 + (int)__builtin_ctzll(mask);
      if (inr) {
        int pos = cnt + (int)__builtin_popcountll(mask & ((1ull << lane) - 1ull));
        if (pos < NSAMP) out[pos] = p;
      }
      cnt += (int)__builtin_popcountll(mask);
      if (cnt >= NSAMP) break;
    }
  }
  if (lane >= cnt && lane < NSAMP) out[lane] = first;
}

// ---------------------------------------------------------------------------
// Stage 4a: layer-1 GEMM with FUSED gather (no X0 materialization).
// Column layout permuted to [pts(64) | dxyz(3) | pad]; weights permuted to
// match while staging. 64x64 tile per block, 256 threads.
// ---------------------------------------------------------------------------
__global__ __launch_bounds__(256) void mlp_gemm_gather(
    const float* __restrict__ xyz, const float* __restrict__ points,
    const float* __restrict__ new_xyz, const int* __restrict__ gidx,
    const float* __restrict__ Wg, const float* __restrict__ bias,
    float* __restrict__ Yg, float* __restrict__ partials) {
  constexpr int O = 64, OJ = 4, KP4 = 17;
  __shared__ __align__(16) float sX[64 * 68];
  __shared__ __align__(16) float sWt[68 * O];
  const int t = threadIdx.x;
  const int m0 = blockIdx.x * 64;

  // stage W with permuted rows: k<64 -> W[o*67+k+3]; 64..66 -> W[o*67+k-64]; 67 -> 0
  for (int i = t; i < O * 68; i += 256) {
    int k = i >> 6, o = i & 63;
    float w;
    if (k < 64) w = Wg[o * 67 + k + 3];
    else if (k < 67) w = Wg[o * 67 + (k - 64)];
    else w = 0.0f;
    sWt[k * O + o] = w;
  }
  // stage X tile directly from gathered points/xyz
  {
    int r = t >> 2, q = t & 3;
    int m = m0 + r;
    int idx = gidx[m];
    int b = m >> 15;
    const float* prow = points + ((size_t)b * NPTS + idx) * 64;
#pragma unroll
    for (int c4 = q; c4 < 16; c4 += 4)
      *(float4*)&sX[r * 68 + 4 * c4] = *(const float4*)(prow + 4 * c4);
    if (q == 0) {
      int g = m >> 5;
      const float* xr = xyz + ((size_t)b * NPTS + idx) * 3;
      sX[r * 68 + 64] = __fsub_rn(xr[0], new_xyz[g * 3 + 0]);
      sX[r * 68 + 65] = __fsub_rn(xr[1], new_xyz[g * 3 + 1]);
      sX[r * 68 + 66] = __fsub_rn(xr[2], new_xyz[g * 3 + 2]);
      sX[r * 68 + 67] = 0.0f;
    }
  }
  __syncthreads();

  const int to = t & 15, tm = t >> 4;
  float acc[4][OJ];
#pragma unroll
  for (int i = 0; i < 4; ++i)
#pragma unroll
    for (int j = 0; j < OJ; ++j) acc[i][j] = 0.0f;

#pragma unroll
  for (int k4 = 0; k4 < KP4; ++k4) {
    float xs[4][4];
#pragma unroll
    for (int i = 0; i < 4; ++i) {
      float4 v = *(const float4*)&sX[(4 * tm + i) * 68 + 4 * k4];
      xs[i][0] = v.x; xs[i][1] = v.y; xs[i][2] = v.z; xs[i][3] = v.w;
    }
#pragma unroll
    for (int kk = 0; kk < 4; ++kk) {
      float4 wq = *(const float4*)&sWt[(4 * k4 + kk) * O + OJ * to];
      float wv[4] = {wq.x, wq.y, wq.z, wq.w};
#pragma unroll
      for (int i = 0; i < 4; ++i) {
        float xv = xs[i][kk];
#pragma unroll
        for (int j = 0; j < OJ; ++j) acc[i][j] = fmaf(xv, wv[j], acc[i][j]);
      }
    }
  }
#pragma unroll
  for (int j = 0; j < OJ; ++j) {
    float bb = bias[OJ * to + j];
#pragma unroll
    for (int i = 0; i < 4; ++i) acc[i][j] += bb;
  }
  float ps[OJ], ss[OJ];
#pragma unroll
  for (int j = 0; j < OJ; ++j) {
    ps[j] = ((acc[0][j] + acc[1][j]) + (acc[2][j] + acc[3][j]));
    ss[j] = ((acc[0][j] * acc[0][j] + acc[1][j] * acc[1][j]) +
             (acc[2][j] * acc[2][j] + acc[3][j] * acc[3][j]));
  }
  __syncthreads();
#pragma unroll
  for (int j = 0; j < OJ; ++j) {
    int o = OJ * to + j;
    sX[tm * O + o] = ps[j];
    sX[16 * O + tm * O + o] = ss[j];
  }
  __syncthreads();
  if (t < O) {
    float s1 = 0.0f, s2 = 0.0f;
#pragma unroll
    for (int r2 = 0; r2 < 16; ++r2) { s1 += sX[r2 * O + t]; s2 += sX[16 * O + r2 * O + t]; }
    partials[(size_t)t * NBLK + blockIdx.x] = s1;
    partials[(size_t)(O + t) * NBLK + blockIdx.x] = s2;
  }
#pragma unroll
  for (int i = 0; i < 4; ++i)
    *(float4*)&Yg[(size_t)(m0 + 4 * tm + i) * O + OJ * to] =
        make_float4(acc[i][0], acc[i][1], acc[i][2], acc[i][3]);
}

// ---------------------------------------------------------------------------
// Stage 4b: MLP layer GEMM (layers 2,3). 64xO tile per block, 256 threads.
// Applies previous layer's BN+ReLU (a,d) while staging input.
// DO_MM: max/min-pool pre-activations over k (32 rows) instead of writing Y.
// ---------------------------------------------------------------------------
template<int O, bool WRITE_Y, bool DO_MM>
__global__ __launch_bounds__(256) void mlp_gemm(const float* __restrict__ Xg,
                                                const float* __restrict__ Wg,
                                                const float* __restrict__ bias,
                                                const float* __restrict__ ad,
                                                float* __restrict__ Yg,
                                                float* __restrict__ partials,
                                                float* __restrict__ mm) {
  constexpr int KDIM = 64, KP4 = 16;
  constexpr int OJ = O / 16;            // 4 or 8
  __shared__ __align__(16) float sX[64 * 68];
  __shared__ __align__(16) float sWt[KDIM * O];
  const int t = threadIdx.x;
  const int m0 = blockIdx.x * 64;

  for (int i = t; i < O * KDIM; i += 256) {
    int k = i / O;
    int o = i - k * O;
    sWt[k * O + o] = Wg[o * KDIM + k];
  }
  {
    int r = t >> 2, q = t & 3;
    const float* src = Xg + (size_t)(m0 + r) * KDIM;
    for (int c4 = q; c4 < KP4; c4 += 4) {
      float4 v = *(const float4*)(src + 4 * c4);
      float4 a = *(const float4*)(ad + 4 * c4);
      float4 d = *(const float4*)(ad + 128 + 4 * c4);
      v.x = fmaxf(fmaf(a.x, v.x, d.x), 0.0f);
      v.y = fmaxf(fmaf(a.y, v.y, d.y), 0.0f);
      v.z = fmaxf(fmaf(a.z, v.z, d.z), 0.0f);
      v.w = fmaxf(fmaf(a.w, v.w, d.w), 0.0f);
      *(float4*)&sX[r * 68 + 4 * c4] = v;
    }
  }
  __syncthreads();

  const int to = t & 15, tm = t >> 4;
  float acc[4][OJ];
#pragma unroll
  for (int i = 0; i < 4; ++i)
#pragma unroll
    for (int j = 0; j < OJ; ++j) acc[i][j] = 0.0f;

#pragma unroll
  for (int k4 = 0; k4 < KP4; ++k4) {
    float xs[4][4];
#pragma unroll
    for (int i = 0; i < 4; ++i) {
      float4 v = *(const float4*)&sX[(4 * tm + i) * 68 + 4 * k4];
      xs[i][0] = v.x; xs[i][1] = v.y; xs[i][2] = v.z; xs[i][3] = v.w;
    }
#pragma unroll
    for (int kk = 0; kk < 4; ++kk) {
      float wv[OJ];
#pragma unroll
      for (int j4 = 0; j4 < OJ / 4; ++j4) {
        float4 wq = *(const float4*)&sWt[(4 * k4 + kk) * O + OJ * to + 4 * j4];
        wv[4 * j4 + 0] = wq.x; wv[4 * j4 + 1] = wq.y;
        wv[4 * j4 + 2] = wq.z; wv[4 * j4 + 3] = wq.w;
      }
#pragma unroll
      for (int i = 0; i < 4; ++i) {
        float xv = xs[i][kk];
#pragma unroll
        for (int j = 0; j < OJ; ++j) acc[i][j] = fmaf(xv, wv[j], acc[i][j]);
      }
    }
  }
#pragma unroll
  for (int j = 0; j < OJ; ++j) {
    float bb = bias[OJ * to + j];
#pragma unroll
    for (int i = 0; i < 4; ++i) acc[i][j] += bb;
  }
  float ps[OJ], ss[OJ];
#pragma unroll
  for (int j = 0; j < OJ; ++j) {
    ps[j] = ((acc[0][j] + acc[1][j]) + (acc[2][j] + acc[3][j]));
    ss[j] = ((acc[0][j] * acc[0][j] + acc[1][j] * acc[1][j]) +
             (acc[2][j] * acc[2][j] + acc[3][j] * acc[3][j]));
  }
  __syncthreads();
#pragma unroll
  for (int j = 0; j < OJ; ++j) {
    int o = OJ * to + j;
    sX[tm * O + o] = ps[j];
    sX[16 * O + tm * O + o] = ss[j];
  }
  __syncthreads();
  if (t < O) {
    float s1 = 0.0f, s2 = 0.0f;
#pragma unroll
    for (int r2 = 0; r2 < 16; ++r2) { s1 += sX[r2 * O + t]; s2 += sX[16 * O + r2 * O + t]; }
    partials[(size_t)t * NBLK + blockIdx.x] = s1;
    partials[(size_t)(O + t) * NBLK + blockIdx.x] = s2;
  }
  if constexpr (WRITE_Y) {
#pragma unroll
    for (int i = 0; i < 4; ++i) {
#pragma unroll
      for (int j4 = 0; j4 < OJ / 4; ++j4) {
        *(float4*)&Yg[(size_t)(m0 + 4 * tm + i) * O + OJ * to + 4 * j4] =
            make_float4(acc[i][4 * j4 + 0], acc[i][4 * j4 + 1],
                        acc[i][4 * j4 + 2], acc[i][4 * j4 + 3]);
      }
    }
  }
  if constexpr (DO_MM) {
    float vmx[OJ], vmn[OJ];
#pragma unroll
    for (int j = 0; j < OJ; ++j) {
      vmx[j] = fmaxf(fmaxf(acc[0][j], acc[1][j]), fmaxf(acc[2][j], acc[3][j]));
      vmn[j] = fminf(fminf(acc[0][j], acc[1][j]), fminf(acc[2][j], acc[3][j]));
    }
    __syncthreads();
#pragma unroll
    for (int j = 0; j < OJ; ++j) {
      int o = OJ * to + j;
      sX[tm * O + o] = vmx[j];
      sX[16 * O + tm * O + o] = vmn[j];
    }
    __syncthreads();
    int g = t >> 7, o = t & 127;
    float mx = sX[(g * 8) * O + o];
    float mn = sX[16 * O + (g * 8) * O + o];
#pragma unroll
    for (int r2 = 1; r2 < 8; ++r2) {
      mx = fmaxf(mx, sX[(g * 8 + r2) * O + o]);
      mn = fminf(mn, sX[16 * O + (g * 8 + r2) * O + o]);
    }
    int row = (m0 >> 5) + g;
    mm[(size_t)row * O + o] = mx;
    mm[(size_t)8192 * O + (size_t)row * O + o] = mn;
  }
}

// ---------------------------------------------------------------------------
// BN finalize: reduce 4096 partials per channel -> (a, d), a=g*rsigma,
// d = bt - mu*a. ad layout: a at [0..O), d at [128..128+O).
// ---------------------------------------------------------------------------
__global__ __launch_bounds__(256) void bn_finalize(const float* __restrict__ partials,
                                                   const float* __restrict__ g,
                                                   const float* __restrict__ bt,
                                                   float* __restrict__ ad, int O) {
  int o = blockIdx.x, t = threadIdx.x;
  const float* p1 = partials + (size_t)o * NBLK;
  const float* p2 = partials + (size_t)(O + o) * NBLK;
  float s1 = 0.0f, s2 = 0.0f;
  for (int i = t; i < NBLK; i += 256) { s1 += p1[i]; s2 += p2[i]; }
  __shared__ float r1[4], r2[4];
#pragma unroll
  for (int off = 32; off >= 1; off >>= 1) {
    s1 += __shfl_down(s1, off, 64);
    s2 += __shfl_down(s2, off, 64);
  }
  if ((t & 63) == 0) { r1[t >> 6] = s1; r2[t >> 6] = s2; }
  __syncthreads();
  if (t == 0) {
    float S1 = (r1[0] + r1[1]) + (r1[2] + r1[3]);
    float S2 = (r2[0] + r2[1]) + (r2[2] + r2[3]);
    const float invM = 1.0f / (float)MTOT;
    float mu = S1 * invM;
    float var = S2 * invM - mu * mu;
    float rs = 1.0f / sqrtf(var + 1e-5f);
    float a = g[o] * rs;
    ad[o] = a;
    ad[128 + o] = bt[o] - mu * a;
  }
}

// ---------------------------------------------------------------------------
// Final: new_points[(b,s),o] = relu(a * (a>=0 ? max : min) + d)
// ---------------------------------------------------------------------------
__global__ __launch_bounds__(256) void final_kernel(const float* __restrict__ mm,
                                                    const float* __restrict__ ad,
                                                    float* __restrict__ out) {
  int gid = blockIdx.x * 256 + threadIdx.x;   // 8192*128 exactly
  int o = gid & 127;
  float a = ad[o], d = ad[128 + o];
  float y = (a >= 0.0f) ? mm[gid] : mm[8192 * 128 + gid];
  out[gid] = fmaxf(fmaf(a, y, d), 0.0f);
}

extern "C" void kernel_launch(void* const* d_in, const int* in_sizes, int n_in,
                              void* d_out, int out_size, void* d_ws, size_t ws_size,
                              hipStream_t stream) {
  (void)in_sizes; (void)n_in; (void)out_size; (void)ws_size;
  const float* xyz    = (const float*)d_in[0];
  const float* points = (const float*)d_in[1];
  const float* w0  = (const float*)d_in[2];
  const float* b0  = (const float*)d_in[3];
  const float* g0  = (const float*)d_in[4];
  const float* bt0 = (const float*)d_in[5];
  const float* w1  = (const float*)d_in[6];
  const float* b1  = (const float*)d_in[7];
  const float* g1  = (const float*)d_in[8];
  const float* bt1 = (const float*)d_in[9];
  const float* w2  = (const float*)d_in[10];
  const float* b2  = (const float*)d_in[11];
  const float* g2  = (const float*)d_in[12];
  const float* bt2 = (const float*)d_in[13];

  float* out      = (float*)d_out;
  float* new_xyz  = out;                 // 8*1024*3 = 24576 floats
  float* out_pts  = out + 24576;         // 8*1024*128 floats

  float* wsf  = (float*)d_ws;
  int*   gidx = (int*)d_ws;                          // 262144 ints
  float* Y2   = wsf + 262144;                        // (old X0 region) 262144*64
  float* Y1   = Y2 + (size_t)MTOT * 68;              // 262144*64
  float* part = Y1 + (size_t)MTOT * 64;              // 2*128*4096
  float* ad1  = part + 2 * 128 * NBLK;               // 256
  float* ad2  = ad1 + 256;
  float* ad3  = ad2 + 256;
  float* mm   = ad3 + 256;                           // 2*8192*128

  fps_kernel<<<NB, 256, 0, stream>>>(xyz, new_xyz);
  ballq_kernel<<<(NB * NPT * 64) / 256, 256, 0, stream>>>(xyz, new_xyz, gidx);

  mlp_gemm_gather<<<NBLK, 256, 0, stream>>>(xyz, points, new_xyz, gidx,
                                            w0, b0, Y1, part);
  bn_finalize<<<64, 256, 0, stream>>>(part, g0, bt0, ad1, 64);

  mlp_gemm<64, true, false><<<NBLK, 256, 0, stream>>>(
      Y1, w1, b1, ad1, Y2, part, nullptr);
  bn_finalize<<<64, 256, 0, stream>>>(part, g1, bt1, ad2, 64);

  mlp_gemm<128, false, true><<<NBLK, 256, 0, stream>>>(
      Y2, w2, b2, ad2, nullptr, part, mm);
  bn_finalize<<<128, 256, 0, stream>>>(part, g2, bt2, ad3, 128);

  final_kernel<<<(8192 * 128) / 256, 256, 0, stream>>>(mm, ad3, out_pts);
}

// Round 6
// 918.262 us; speedup vs baseline: 1.3038x; 1.0785x over previous
//
#include <hip/hip_runtime.h>
#include <cmath>

// Problem constants
#define NB 8
#define NPTS 4096
#define NPT 1024
#define NSAMP 32
#define MTOT (NB*NPT*NSAMP)   // 262144 rows for the MLP
#define NBLK 4096             // MTOT/64 GEMM blocks

typedef float v2f __attribute__((ext_vector_type(2)));

// ---------------------------------------------------------------------------
// Stage 1: farthest point sampling. One block of 8 waves per batch.
// Bitwise-exact f32 replication of the reference (packed mul/add with
// contraction OFF; (dx2+dy2)+dz2 order; argmax first-index tie-break).
// Serial-latency-minimized step:
//   dist (36 indep pk ops) -> pk value tree -> 32-bit DPP wave max ->
//   readlane -> 8x v_cmp_eq (ballots) -> SALU first-nonzero scan ->
//   uniform u64 key, lane0 ds_write -> barrier -> 8-slot u64 sel tree ->
//   sxyz[far] broadcast read. No per-lane index recovery, no VALU cmp/sel
//   chains, no vmem in loop.
// ---------------------------------------------------------------------------
__global__ __launch_bounds__(512) void fps_kernel(const float* __restrict__ xyz,
                                                  float* __restrict__ new_xyz) {
#pragma clang fp contract(off)
  const int b = blockIdx.x;
  const int t = threadIdx.x;          // 0..511
  const int wv = t >> 6;              // 0..7
  const int lane = t & 63;
  __shared__ float4 sxyz[NPTS];                  // 64 KiB
  __shared__ float4 sout[NPT];                   // 16 KiB centroid history
  __shared__ unsigned long long skey[2][8];      // parity-buffered wave keys
  const float* X = xyz + (size_t)b * NPTS * 3;
  v2f px[4], py[4], pz[4], dist[4];
#pragma unroll
  for (int i = 0; i < 4; ++i) {
    int p0 = (2 * i) * 512 + t;
    int p1 = (2 * i + 1) * 512 + t;
    float x0 = X[p0 * 3 + 0], y0 = X[p0 * 3 + 1], z0 = X[p0 * 3 + 2];
    float x1 = X[p1 * 3 + 0], y1 = X[p1 * 3 + 1], z1 = X[p1 * 3 + 2];
    px[i] = (v2f){x0, x1}; py[i] = (v2f){y0, y1}; pz[i] = (v2f){z0, z1};
    sxyz[p0] = make_float4(x0, y0, z0, 0.0f);
    sxyz[p1] = make_float4(x1, y1, z1, 0.0f);
    dist[i] = (v2f){1e10f, 1e10f};
  }
  __syncthreads();
  float ccx = X[0], ccy = X[1], ccz = X[2];      // first centroid = point 0
  for (int s = 0; s < NPT; ++s) {
    if (t == 0) sout[s] = make_float4(ccx, ccy, ccz, 0.0f);
    v2f cx = (v2f){ccx, ccx}, cy = (v2f){ccy, ccy}, cz = (v2f){ccz, ccz};
    v2f nd[4];
#pragma unroll
    for (int i = 0; i < 4; ++i) {
      v2f dx = px[i] - cx;
      v2f dy = py[i] - cy;
      v2f dz = pz[i] - cz;
      v2f d = (dx * dx + dy * dy) + dz * dz;     // contract(off): ref order
      v2f m = __builtin_elementwise_min(dist[i], d);
      dist[i] = m;
      nd[i] = m;
    }
    // per-lane max value (no index tracking): depth-2 pk tree + halves merge
    v2f t01 = __builtin_elementwise_max(nd[0], nd[1]);
    v2f t23 = __builtin_elementwise_max(nd[2], nd[3]);
    v2f t03 = __builtin_elementwise_max(t01, t23);
    float lmax = fmaxf(t03.x, t03.y);
    // 32-bit DPP wave max on value bits (all values >= +0 -> unsigned order)
    unsigned km = __float_as_uint(lmax);
    {
      unsigned o;
      o = (unsigned)__builtin_amdgcn_update_dpp(0, (int)km, 0x111, 0xf, 0xf, false);
      km = o > km ? o : km;   // row_shr:1
      o = (unsigned)__builtin_amdgcn_update_dpp(0, (int)km, 0x112, 0xf, 0xf, false);
      km = o > km ? o : km;   // row_shr:2
      o = (unsigned)__builtin_amdgcn_update_dpp(0, (int)km, 0x114, 0xf, 0xf, false);
      km = o > km ? o : km;   // row_shr:4
      o = (unsigned)__builtin_amdgcn_update_dpp(0, (int)km, 0x118, 0xf, 0xf, false);
      km = o > km ? o : km;   // row_shr:8
      o = (unsigned)__builtin_amdgcn_update_dpp(0, (int)km, 0x142, 0xf, 0xf, false);
      km = o > km ? o : km;   // row_bcast:15
      o = (unsigned)__builtin_amdgcn_update_dpp(0, (int)km, 0x143, 0xf, 0xf, false);
      km = o > km ? o : km;   // row_bcast:31
    }
    unsigned wmax = (unsigned)__builtin_amdgcn_readlane((int)km, 63);  // uniform
    // ballots per ordinal: ordinal k = point k*512 + t
    unsigned long long m0 = __ballot(__float_as_uint(nd[0].x) == wmax);
    unsigned long long m1 = __ballot(__float_as_uint(nd[0].y) == wmax);
    unsigned long long m2 = __ballot(__float_as_uint(nd[1].x) == wmax);
    unsigned long long m3 = __ballot(__float_as_uint(nd[1].y) == wmax);
    unsigned long long m4 = __ballot(__float_as_uint(nd[2].x) == wmax);
    unsigned long long m5 = __ballot(__float_as_uint(nd[2].y) == wmax);
    unsigned long long m6 = __ballot(__float_as_uint(nd[3].x) == wmax);
    unsigned long long m7 = __ballot(__float_as_uint(nd[3].y) == wmax);
    // first-nonzero scan, prefer smallest ordinal (all uniform -> SALU)
    unsigned long long mk = m7; int ord = 7;
    if (m6) { mk = m6; ord = 6; }
    if (m5) { mk = m5; ord = 5; }
    if (m4) { mk = m4; ord = 4; }
    if (m3) { mk = m3; ord = 3; }
    if (m2) { mk = m2; ord = 2; }
    if (m1) { mk = m1; ord = 1; }
    if (m0) { mk = m0; ord = 0; }
    int wlane = (int)__builtin_ctzll(mk);        // smallest lane in this wave
    int idx = ord * 512 + wv * 64 + wlane;       // global point index
    // key: higher value wins; equal value -> smaller index wins
    unsigned long long key = ((unsigned long long)wmax << 32)
                           | (unsigned int)(~idx);
    int par = s & 1;
    if (lane == 0) skey[par][wv] = key;          // uniform -> 8B store
    __syncthreads();
    // 8-slot u64 max-sel tree
    const ulonglong2* sk = (const ulonglong2*)skey[par];
    ulonglong2 A = sk[0], B = sk[1], C = sk[2], D = sk[3];
    unsigned long long a = A.x > A.y ? A.x : A.y;
    unsigned long long bq = B.x > B.y ? B.x : B.y;
    unsigned long long c = C.x > C.y ? C.x : C.y;
    unsigned long long dq = D.x > D.y ? D.x : D.y;
    unsigned long long ab = a > bq ? a : bq;
    unsigned long long cd = c > dq ? c : dq;
    unsigned long long kf = ab > cd ? ab : cd;
    int far = (int)(~(unsigned int)kf) & (NPTS - 1);
    float4 cc = sxyz[far];
    ccx = cc.x; ccy = cc.y; ccz = cc.z;
  }
  __syncthreads();
  float* outp = new_xyz + (size_t)b * NPT * 3;
  for (int j = t; j < NPT; j += 512) {
    float4 c = sout[j];
    outp[3 * j + 0] = c.x; outp[3 * j + 1] = c.y; outp[3 * j + 2] = c.z;
  }
}

// ---------------------------------------------------------------------------
// Stage 2: ball query. One wave per (b,s). First 32 indices in ascending order
// with dist <= r^2; pad with first match.
// ---------------------------------------------------------------------------
__global__ __launch_bounds__(256) void ballq_kernel(const float* __restrict__ xyz,
                                                    const float* __restrict__ new_xyz,
                                                    int* __restrict__ gidx) {
  int w = (blockIdx.x * 256 + threadIdx.x) >> 6;   // 8192 waves
  int lane = threadIdx.x & 63;
  int b = w >> 10;
  const float* X = xyz + (size_t)b * NPTS * 3;
  float cx = new_xyz[w * 3 + 0], cy = new_xyz[w * 3 + 1], cz = new_xyz[w * 3 + 2];
  int* out = gidx + (size_t)w * NSAMP;
  int cnt = 0, first = -1;
  for (int c = 0; c < NPTS / 64; ++c) {
    int p = c * 64 + lane;
    float dx = __fsub_rn(X[p * 3 + 0], cx);
    float dy = __fsub_rn(X[p * 3 + 1], cy);
    float dz = __fsub_rn(X[p * 3 + 2], cz);
    float d = __fadd_rn(__fadd_rn(__fmul_rn(dx, dx), __fmul_rn(dy, dy)), __fmul_rn(dz, dz));
    bool inr = !(d > 0.04f);   // f32(0.2**2) == 0.04f
    unsigned long long mask = __ballot(inr);
    if (mask) {
      if (first < 0) first = c * 64 + (int)__builtin_ctzll(mask);
      if (inr) {
        int pos = cnt + (int)__builtin_popcountll(mask & ((1ull << lane) - 1ull));
        if (pos < NSAMP) out[pos] = p;
      }
      cnt += (int)__builtin_popcountll(mask);
      if (cnt >= NSAMP) break;
    }
  }
  if (lane >= cnt && lane < NSAMP) out[lane] = first;
}

// ---------------------------------------------------------------------------
// Stage 4a: layer-1 GEMM with FUSED gather (no X0 materialization).
// Column layout permuted to [pts(64) | dxyz(3) | pad]; weights permuted to
// match while staging. 64x64 tile per block, 256 threads.
// ---------------------------------------------------------------------------
__global__ __launch_bounds__(256) void mlp_gemm_gather(
    const float* __restrict__ xyz, const float* __restrict__ points,
    const float* __restrict__ new_xyz, const int* __restrict__ gidx,
    const float* __restrict__ Wg, const float* __restrict__ bias,
    float* __restrict__ Yg, float* __restrict__ partials) {
  constexpr int O = 64, OJ = 4, KP4 = 17;
  __shared__ __align__(16) float sX[64 * 68];
  __shared__ __align__(16) float sWt[68 * O];
  const int t = threadIdx.x;
  const int m0 = blockIdx.x * 64;

  // stage W with permuted rows: k<64 -> W[o*67+k+3]; 64..66 -> W[o*67+k-64]; 67 -> 0
  for (int i = t; i < O * 68; i += 256) {
    int k = i >> 6, o = i & 63;
    float w;
    if (k < 64) w = Wg[o * 67 + k + 3];
    else if (k < 67) w = Wg[o * 67 + (k - 64)];
    else w = 0.0f;
    sWt[k * O + o] = w;
  }
  // stage X tile directly from gathered points/xyz
  {
    int r = t >> 2, q = t & 3;
    int m = m0 + r;
    int idx = gidx[m];
    int b = m >> 15;
    const float* prow = points + ((size_t)b * NPTS + idx) * 64;
#pragma unroll
    for (int c4 = q; c4 < 16; c4 += 4)
      *(float4*)&sX[r * 68 + 4 * c4] = *(const float4*)(prow + 4 * c4);
    if (q == 0) {
      int g = m >> 5;
      const float* xr = xyz + ((size_t)b * NPTS + idx) * 3;
      sX[r * 68 + 64] = __fsub_rn(xr[0], new_xyz[g * 3 + 0]);
      sX[r * 68 + 65] = __fsub_rn(xr[1], new_xyz[g * 3 + 1]);
      sX[r * 68 + 66] = __fsub_rn(xr[2], new_xyz[g * 3 + 2]);
      sX[r * 68 + 67] = 0.0f;
    }
  }
  __syncthreads();

  const int to = t & 15, tm = t >> 4;
  float acc[4][OJ];
#pragma unroll
  for (int i = 0; i < 4; ++i)
#pragma unroll
    for (int j = 0; j < OJ; ++j) acc[i][j] = 0.0f;

#pragma unroll
  for (int k4 = 0; k4 < KP4; ++k4) {
    float xs[4][4];
#pragma unroll
    for (int i = 0; i < 4; ++i) {
      float4 v = *(const float4*)&sX[(4 * tm + i) * 68 + 4 * k4];
      xs[i][0] = v.x; xs[i][1] = v.y; xs[i][2] = v.z; xs[i][3] = v.w;
    }
#pragma unroll
    for (int kk = 0; kk < 4; ++kk) {
      float4 wq = *(const float4*)&sWt[(4 * k4 + kk) * O + OJ * to];
      float wv[4] = {wq.x, wq.y, wq.z, wq.w};
#pragma unroll
      for (int i = 0; i < 4; ++i) {
        float xv = xs[i][kk];
#pragma unroll
        for (int j = 0; j < OJ; ++j) acc[i][j] = fmaf(xv, wv[j], acc[i][j]);
      }
    }
  }
#pragma unroll
  for (int j = 0; j < OJ; ++j) {
    float bb = bias[OJ * to + j];
#pragma unroll
    for (int i = 0; i < 4; ++i) acc[i][j] += bb;
  }
  float ps[OJ], ss[OJ];
#pragma unroll
  for (int j = 0; j < OJ; ++j) {
    ps[j] = ((acc[0][j] + acc[1][j]) + (acc[2][j] + acc[3][j]));
    ss[j] = ((acc[0][j] * acc[0][j] + acc[1][j] * acc[1][j]) +
             (acc[2][j] * acc[2][j] + acc[3][j] * acc[3][j]));
  }
  __syncthreads();
#pragma unroll
  for (int j = 0; j < OJ; ++j) {
    int o = OJ * to + j;
    sX[tm * O + o] = ps[j];
    sX[16 * O + tm * O + o] = ss[j];
  }
  __syncthreads();
  if (t < O) {
    float s1 = 0.0f, s2 = 0.0f;
#pragma unroll
    for (int r2 = 0; r2 < 16; ++r2) { s1 += sX[r2 * O + t]; s2 += sX[16 * O + r2 * O + t]; }
    partials[(size_t)t * NBLK + blockIdx.x] = s1;
    partials[(size_t)(O + t) * NBLK + blockIdx.x] = s2;
  }
#pragma unroll
  for (int i = 0; i < 4; ++i)
    *(float4*)&Yg[(size_t)(m0 + 4 * tm + i) * O + OJ * to] =
        make_float4(acc[i][0], acc[i][1], acc[i][2], acc[i][3]);
}

// ---------------------------------------------------------------------------
// Stage 4b: MLP layer GEMM (layers 2,3). 64xO tile per block, 256 threads.
// Applies previous layer's BN+ReLU (a,d) while staging input.
// DO_MM: max/min-pool pre-activations over k (32 rows) instead of writing Y.
// ---------------------------------------------------------------------------
template<int O, bool WRITE_Y, bool DO_MM>
__global__ __launch_bounds__(256) void mlp_gemm(const float* __restrict__ Xg,
                                                const float* __restrict__ Wg,
                                                const float* __restrict__ bias,
                                                const float* __restrict__ ad,
                                                float* __restrict__ Yg,
                                                float* __restrict__ partials,
                                                float* __restrict__ mm) {
  constexpr int KDIM = 64, KP4 = 16;
  constexpr int OJ = O / 16;            // 4 or 8
  __shared__ __align__(16) float sX[64 * 68];
  __shared__ __align__(16) float sWt[KDIM * O];
  const int t = threadIdx.x;
  const int m0 = blockIdx.x * 64;

  for (int i = t; i < O * KDIM; i += 256) {
    int k = i / O;
    int o = i - k * O;
    sWt[k * O + o] = Wg[o * KDIM + k];
  }
  {
    int r = t >> 2, q = t & 3;
    const float* src = Xg + (size_t)(m0 + r) * KDIM;
    for (int c4 = q; c4 < KP4; c4 += 4) {
      float4 v = *(const float4*)(src + 4 * c4);
      float4 a = *(const float4*)(ad + 4 * c4);
      float4 d = *(const float4*)(ad + 128 + 4 * c4);
      v.x = fmaxf(fmaf(a.x, v.x, d.x), 0.0f);
      v.y = fmaxf(fmaf(a.y, v.y, d.y), 0.0f);
      v.z = fmaxf(fmaf(a.z, v.z, d.z), 0.0f);
      v.w = fmaxf(fmaf(a.w, v.w, d.w), 0.0f);
      *(float4*)&sX[r * 68 + 4 * c4] = v;
    }
  }
  __syncthreads();

  const int to = t & 15, tm = t >> 4;
  float acc[4][OJ];
#pragma unroll
  for (int i = 0; i < 4; ++i)
#pragma unroll
    for (int j = 0; j < OJ; ++j) acc[i][j] = 0.0f;

#pragma unroll
  for (int k4 = 0; k4 < KP4; ++k4) {
    float xs[4][4];
#pragma unroll
    for (int i = 0; i < 4; ++i) {
      float4 v = *(const float4*)&sX[(4 * tm + i) * 68 + 4 * k4];
      xs[i][0] = v.x; xs[i][1] = v.y; xs[i][2] = v.z; xs[i][3] = v.w;
    }
#pragma unroll
    for (int kk = 0; kk < 4; ++kk) {
      float wv[OJ];
#pragma unroll
      for (int j4 = 0; j4 < OJ / 4; ++j4) {
        float4 wq = *(const float4*)&sWt[(4 * k4 + kk) * O + OJ * to + 4 * j4];
        wv[4 * j4 + 0] = wq.x; wv[4 * j4 + 1] = wq.y;
        wv[4 * j4 + 2] = wq.z; wv[4 * j4 + 3] = wq.w;
      }
#pragma unroll
      for (int i = 0; i < 4; ++i) {
        float xv = xs[i][kk];
#pragma unroll
        for (int j = 0; j < OJ; ++j) acc[i][j] = fmaf(xv, wv[j], acc[i][j]);
      }
    }
  }
#pragma unroll
  for (int j = 0; j < OJ; ++j) {
    float bb = bias[OJ * to + j];
#pragma unroll
    for (int i = 0; i < 4; ++i) acc[i][j] += bb;
  }
  float ps[OJ], ss[OJ];
#pragma unroll
  for (int j = 0; j < OJ; ++j) {
    ps[j] = ((acc[0][j] + acc[1][j]) + (acc[2][j] + acc[3][j]));
    ss[j] = ((acc[0][j] * acc[0][j] + acc[1][j] * acc[1][j]) +
             (acc[2][j] * acc[2][j] + acc[3][j] * acc[3][j]));
  }
  __syncthreads();
#pragma unroll
  for (int j = 0; j < OJ; ++j) {
    int o = OJ * to + j;
    sX[tm * O + o] = ps[j];
    sX[16 * O + tm * O + o] = ss[j];
  }
  __syncthreads();
  if (t < O) {
    float s1 = 0.0f, s2 = 0.0f;
#pragma unroll
    for (int r2 = 0; r2 < 16; ++r2) { s1 += sX[r2 * O + t]; s2 += sX[16 * O + r2 * O + t]; }
    partials[(size_t)t * NBLK + blockIdx.x] = s1;
    partials[(size_t)(O + t) * NBLK + blockIdx.x] = s2;
  }
  if constexpr (WRITE_Y) {
#pragma unroll
    for (int i = 0; i < 4; ++i) {
#pragma unroll
      for (int j4 = 0; j4 < OJ / 4; ++j4) {
        *(float4*)&Yg[(size_t)(m0 + 4 * tm + i) * O + OJ * to + 4 * j4] =
            make_float4(acc[i][4 * j4 + 0], acc[i][4 * j4 + 1],
                        acc[i][4 * j4 + 2], acc[i][4 * j4 + 3]);
      }
    }
  }
  if constexpr (DO_MM) {
    float vmx[OJ], vmn[OJ];
#pragma unroll
    for (int j = 0; j < OJ; ++j) {
      vmx[j] = fmaxf(fmaxf(acc[0][j], acc[1][j]), fmaxf(acc[2][j], acc[3][j]));
      vmn[j] = fminf(fminf(acc[0][j], acc[1][j]), fminf(acc[2][j], acc[3][j]));
    }
    __syncthreads();
#pragma unroll
    for (int j = 0; j < OJ; ++j) {
      int o = OJ * to + j;
      sX[tm * O + o] = vmx[j];
      sX[16 * O + tm * O + o] = vmn[j];
    }
    __syncthreads();
    int g = t >> 7, o = t & 127;
    float mx = sX[(g * 8) * O + o];
    float mn = sX[16 * O + (g * 8) * O + o];
#pragma unroll
    for (int r2 = 1; r2 < 8; ++r2) {
      mx = fmaxf(mx, sX[(g * 8 + r2) * O + o]);
      mn = fminf(mn, sX[16 * O + (g * 8 + r2) * O + o]);
    }
    int row = (m0 >> 5) + g;
    mm[(size_t)row * O + o] = mx;
    mm[(size_t)8192 * O + (size_t)row * O + o] = mn;
  }
}

// ---------------------------------------------------------------------------
// BN finalize: reduce 4096 partials per channel -> (a, d), a=g*rsigma,
// d = bt - mu*a. ad layout: a at [0..O), d at [128..128+O).
// ---------------------------------------------------------------------------
__global__ __launch_bounds__(256) void bn_finalize(const float* __restrict__ partials,
                                                   const float* __restrict__ g,
                                                   const float* __restrict__ bt,
                                                   float* __restrict__ ad, int O) {
  int o = blockIdx.x, t = threadIdx.x;
  const float* p1 = partials + (size_t)o * NBLK;
  const float* p2 = partials + (size_t)(O + o) * NBLK;
  float s1 = 0.0f, s2 = 0.0f;
  for (int i = t; i < NBLK; i += 256) { s1 += p1[i]; s2 += p2[i]; }
  __shared__ float r1[4], r2[4];
#pragma unroll
  for (int off = 32; off >= 1; off >>= 1) {
    s1 += __shfl_down(s1, off, 64);
    s2 += __shfl_down(s2, off, 64);
  }
  if ((t & 63) == 0) { r1[t >> 6] = s1; r2[t >> 6] = s2; }
  __syncthreads();
  if (t == 0) {
    float S1 = (r1[0] + r1[1]) + (r1[2] + r1[3]);
    float S2 = (r2[0] + r2[1]) + (r2[2] + r2[3]);
    const float invM = 1.0f / (float)MTOT;
    float mu = S1 * invM;
    float var = S2 * invM - mu * mu;
    float rs = 1.0f / sqrtf(var + 1e-5f);
    float a = g[o] * rs;
    ad[o] = a;
    ad[128 + o] = bt[o] - mu * a;
  }
}

// ---------------------------------------------------------------------------
// Final: new_points[(b,s),o] = relu(a * (a>=0 ? max : min) + d)
// ---------------------------------------------------------------------------
__global__ __launch_bounds__(256) void final_kernel(const float* __restrict__ mm,
                                                    const float* __restrict__ ad,
                                                    float* __restrict__ out) {
  int gid = blockIdx.x * 256 + threadIdx.x;   // 8192*128 exactly
  int o = gid & 127;
  float a = ad[o], d = ad[128 + o];
  float y = (a >= 0.0f) ? mm[gid] : mm[8192 * 128 + gid];
  out[gid] = fmaxf(fmaf(a, y, d), 0.0f);
}

extern "C" void kernel_launch(void* const* d_in, const int* in_sizes, int n_in,
                              void* d_out, int out_size, void* d_ws, size_t ws_size,
                              hipStream_t stream) {
  (void)in_sizes; (void)n_in; (void)out_size; (void)ws_size;
  const float* xyz    = (const float*)d_in[0];
  const float* points = (const float*)d_in[1];
  const float* w0  = (const float*)d_in[2];
  const float* b0  = (const float*)d_in[3];
  const float* g0  = (const float*)d_in[4];
  const float* bt0 = (const float*)d_in[5];
  const float* w1  = (const float*)d_in[6];
  const float* b1  = (const float*)d_in[7];
  const float* g1  = (const float*)d_in[8];
  const float* bt1 = (const float*)d_in[9];
  const float* w2  = (const float*)d_in[10];
  const float* b2  = (const float*)d_in[11];
  const float* g2  = (const float*)d_in[12];
  const float* bt2 = (const float*)d_in[13];

  float* out      = (float*)d_out;
  float* new_xyz  = out;                 // 8*1024*3 = 24576 floats
  float* out_pts  = out + 24576;         // 8*1024*128 floats

  float* wsf  = (float*)d_ws;
  int*   gidx = (int*)d_ws;                          // 262144 ints
  float* Y2   = wsf + 262144;                        // 262144*64
  float* Y1   = Y2 + (size_t)MTOT * 68;              // 262144*64
  float* part = Y1 + (size_t)MTOT * 64;              // 2*128*4096
  float* ad1  = part + 2 * 128 * NBLK;               // 256
  float* ad2  = ad1 + 256;
  float* ad3  = ad2 + 256;
  float* mm   = ad3 + 256;                           // 2*8192*128

  fps_kernel<<<NB, 512, 0, stream>>>(xyz, new_xyz);
  ballq_kernel<<<(NB * NPT * 64) / 256, 256, 0, stream>>>(xyz, new_xyz, gidx);

  mlp_gemm_gather<<<NBLK, 256, 0, stream>>>(xyz, points, new_xyz, gidx,
                                            w0, b0, Y1, part);
  bn_finalize<<<64, 256, 0, stream>>>(part, g0, bt0, ad1, 64);

  mlp_gemm<64, true, false><<<NBLK, 256, 0, stream>>>(
      Y1, w1, b1, ad1, Y2, part, nullptr);
  bn_finalize<<<64, 256, 0, stream>>>(part, g1, bt1, ad2, 64);

  mlp_gemm<128, false, true><<<NBLK, 256, 0, stream>>>(
      Y2, w2, b2, ad2, nullptr, part, mm);
  bn_finalize<<<128, 256, 0, stream>>>(part, g2, bt2, ad3, 128);

  final_kernel<<<(8192 * 128) / 256, 256, 0, stream>>>(mm, ad3, out_pts);
}